// Round 7
// baseline (12055.982 us; speedup 1.0000x reference)
//
#include <hip/hip_runtime.h>
#include <hip/hip_bf16.h>

typedef __attribute__((ext_vector_type(8))) short bf16x8;
typedef __attribute__((ext_vector_type(4))) float f32x4;
typedef unsigned int u32;
typedef unsigned long long u64;

static constexpr int TT = 1024, BB = 256, HH = 256, FF = 73, OO = 35;
static constexpr int NBB = 4;   // batch tiles (64 rows each)
static constexpr int NJ = 8;    // gate-slice blocks per tile (32 cols)
static constexpr int BT = 64;   // batch rows per block
static constexpr int DSLOT = 8; // ring depth
static constexpr int SLOTB = BT * HH * 2;  // 32768 B per slot [64 rows][256 cols] bf16
static constexpr int HFIN_OFF = BB * OO;
static constexpr int CFIN_OFF = HFIN_OFF + 3 * BB * HH;

union FragU { uint4 u; bf16x8 b; };

__device__ __forceinline__ unsigned short f2bf(float f) {
  __hip_bfloat16 h = __float2bfloat16(f);
  union { __hip_bfloat16 h; unsigned short s; } cv; cv.h = h; return cv.s;
}
__device__ __forceinline__ u32 pk2(float a, float b) {
  return (u32)f2bf(a) | ((u32)f2bf(b) << 16);
}
__device__ __forceinline__ uint4 pack8(const float* f) {
  return make_uint4(pk2(f[0], f[1]), pk2(f[2], f[3]), pk2(f[4], f[5]), pk2(f[6], f[7]));
}
__device__ __forceinline__ float fsig(float x) { return 1.f / (1.f + __expf(-x)); }
__device__ __forceinline__ float ftanh(float x) { return 2.f * fsig(2.f * x) - 1.f; }

__device__ __forceinline__ void stg_coh_b32(void* p, u32 v) {
  asm volatile("global_store_dword %0, %1, off sc0 sc1" :: "v"(p), "v"(v) : "memory");
}
__device__ __forceinline__ void vm_drain() {
  asm volatile("s_waitcnt vmcnt(0)" ::: "memory");
}
__device__ __forceinline__ bool ge4(uint4 v, u32 n) {
  return v.x >= n && v.y >= n && v.z >= n && v.w >= n;
}

// Poll three 64B flag regions (own / lower / consumer) in one coherent burst.
// sc0 sc1 on the POLL LOADS is mandatory: without it the loads hit the stale
// per-XCD L2 and spin forever (round-6 hang). Bounded spin = hang insurance.
__device__ __forceinline__ void pollwait(const u32* pO, const u32* pL, const u32* pC,
                                         u32 nO, u32 nL, u32 nC) {
  for (u32 it = 0; it < 500000u; ++it) {
    uint4 a0, a1, a2, a3, b0, b1, b2, b3, c0, c1, c2, c3;
    asm volatile(
        "global_load_dwordx4 %0, %12, off sc0 sc1\n\t"
        "global_load_dwordx4 %1, %12, off offset:16 sc0 sc1\n\t"
        "global_load_dwordx4 %2, %12, off offset:32 sc0 sc1\n\t"
        "global_load_dwordx4 %3, %12, off offset:48 sc0 sc1\n\t"
        "global_load_dwordx4 %4, %13, off sc0 sc1\n\t"
        "global_load_dwordx4 %5, %13, off offset:16 sc0 sc1\n\t"
        "global_load_dwordx4 %6, %13, off offset:32 sc0 sc1\n\t"
        "global_load_dwordx4 %7, %13, off offset:48 sc0 sc1\n\t"
        "global_load_dwordx4 %8, %14, off sc0 sc1\n\t"
        "global_load_dwordx4 %9, %14, off offset:16 sc0 sc1\n\t"
        "global_load_dwordx4 %10, %14, off offset:32 sc0 sc1\n\t"
        "global_load_dwordx4 %11, %14, off offset:48 sc0 sc1\n\t"
        "s_waitcnt vmcnt(0)"
        : "=&v"(a0), "=&v"(a1), "=&v"(a2), "=&v"(a3),
          "=&v"(b0), "=&v"(b1), "=&v"(b2), "=&v"(b3),
          "=&v"(c0), "=&v"(c1), "=&v"(c2), "=&v"(c3)
        : "v"(pO), "v"(pL), "v"(pC)
        : "memory");
    if (ge4(a0, nO) && ge4(a1, nO) && ge4(a2, nO) && ge4(a3, nO) &&
        ge4(b0, nL) && ge4(b1, nL) && ge4(b2, nL) && ge4(b3, nL) &&
        ge4(c0, nC) && ge4(c1, nC) && ge4(c2, nC) && ge4(c3, nC)) return;
    __builtin_amdgcn_s_sleep(1);
  }
  // bound tripped: fall through (finite wrong answer beats an infinite hang)
}

// xa burst: 16 loads in flight, NO waitcnt (drained by the following LD16H).
#define LD16X(basep)                                                            \
  do {                                                                          \
    const char* _x0 = (basep) + vo0;                                            \
    const char* _x1 = (basep) + vo1;                                            \
    asm volatile(                                                               \
        "global_load_dwordx4 %0,  %16, off sc0 sc1\n\t"                         \
        "global_load_dwordx4 %1,  %16, off offset:64 sc0 sc1\n\t"               \
        "global_load_dwordx4 %2,  %16, off offset:128 sc0 sc1\n\t"              \
        "global_load_dwordx4 %3,  %16, off offset:192 sc0 sc1\n\t"              \
        "global_load_dwordx4 %4,  %16, off offset:256 sc0 sc1\n\t"              \
        "global_load_dwordx4 %5,  %16, off offset:320 sc0 sc1\n\t"              \
        "global_load_dwordx4 %6,  %16, off offset:384 sc0 sc1\n\t"              \
        "global_load_dwordx4 %7,  %16, off offset:448 sc0 sc1\n\t"              \
        "global_load_dwordx4 %8,  %17, off sc0 sc1\n\t"                         \
        "global_load_dwordx4 %9,  %17, off offset:64 sc0 sc1\n\t"               \
        "global_load_dwordx4 %10, %17, off offset:128 sc0 sc1\n\t"              \
        "global_load_dwordx4 %11, %17, off offset:192 sc0 sc1\n\t"              \
        "global_load_dwordx4 %12, %17, off offset:256 sc0 sc1\n\t"              \
        "global_load_dwordx4 %13, %17, off offset:320 sc0 sc1\n\t"              \
        "global_load_dwordx4 %14, %17, off offset:384 sc0 sc1\n\t"              \
        "global_load_dwordx4 %15, %17, off offset:448 sc0 sc1"                  \
        : "=&v"(xa[0][0]), "=&v"(xa[0][1]), "=&v"(xa[0][2]), "=&v"(xa[0][3]),   \
          "=&v"(xa[0][4]), "=&v"(xa[0][5]), "=&v"(xa[0][6]), "=&v"(xa[0][7]),   \
          "=&v"(xa[1][0]), "=&v"(xa[1][1]), "=&v"(xa[1][2]), "=&v"(xa[1][3]),   \
          "=&v"(xa[1][4]), "=&v"(xa[1][5]), "=&v"(xa[1][6]), "=&v"(xa[1][7])    \
        : "v"(_x0), "v"(_x1)                                                    \
        : "memory");                                                            \
  } while (0)

// ha burst: 16 loads + vmcnt(0) (drains the LD16X loads too).
#define LD16H(basep)                                                            \
  do {                                                                          \
    const char* _h0 = (basep) + vo0;                                            \
    const char* _h1 = (basep) + vo1;                                            \
    asm volatile(                                                               \
        "global_load_dwordx4 %0,  %16, off sc0 sc1\n\t"                         \
        "global_load_dwordx4 %1,  %16, off offset:64 sc0 sc1\n\t"               \
        "global_load_dwordx4 %2,  %16, off offset:128 sc0 sc1\n\t"              \
        "global_load_dwordx4 %3,  %16, off offset:192 sc0 sc1\n\t"              \
        "global_load_dwordx4 %4,  %16, off offset:256 sc0 sc1\n\t"              \
        "global_load_dwordx4 %5,  %16, off offset:320 sc0 sc1\n\t"              \
        "global_load_dwordx4 %6,  %16, off offset:384 sc0 sc1\n\t"              \
        "global_load_dwordx4 %7,  %16, off offset:448 sc0 sc1\n\t"              \
        "global_load_dwordx4 %8,  %17, off sc0 sc1\n\t"                         \
        "global_load_dwordx4 %9,  %17, off offset:64 sc0 sc1\n\t"               \
        "global_load_dwordx4 %10, %17, off offset:128 sc0 sc1\n\t"              \
        "global_load_dwordx4 %11, %17, off offset:192 sc0 sc1\n\t"              \
        "global_load_dwordx4 %12, %17, off offset:256 sc0 sc1\n\t"              \
        "global_load_dwordx4 %13, %17, off offset:320 sc0 sc1\n\t"              \
        "global_load_dwordx4 %14, %17, off offset:384 sc0 sc1\n\t"              \
        "global_load_dwordx4 %15, %17, off offset:448 sc0 sc1\n\t"              \
        "s_waitcnt vmcnt(0)"                                                    \
        : "=&v"(ha[0][0]), "=&v"(ha[0][1]), "=&v"(ha[0][2]), "=&v"(ha[0][3]),   \
          "=&v"(ha[0][4]), "=&v"(ha[0][5]), "=&v"(ha[0][6]), "=&v"(ha[0][7]),   \
          "=&v"(ha[1][0]), "=&v"(ha[1][1]), "=&v"(ha[1][2]), "=&v"(ha[1][3]),   \
          "=&v"(ha[1][4]), "=&v"(ha[1][5]), "=&v"(ha[1][6]), "=&v"(ha[1][7])    \
        : "v"(_h0), "v"(_h1)                                                    \
        : "memory");                                                            \
  } while (0)

// One block = (layer l, 64-row batch tile bi, 32-col gate slice ji); 4 independent
// waves (mh = 32-row half, nh = 16-col half). No LDS, no __syncthreads: A-frags load
// straight from the coherent ring into registers; per-wave monotonic flags.
template <int KS>  // 16 for l>0 (K=512), 12 for l0 (K=384)
__device__ void lstm_body(int l, int bi, int ji,
    const float* __restrict__ x,
    const float* __restrict__ h0, const float* __restrict__ c0,
    const float* __restrict__ Wih, const float* __restrict__ Whh,
    const float* __restrict__ bih, const float* __restrict__ bhh,
    float* __restrict__ dout, u32* flg, u32* cns, char* ring)
{
  constexpr int KSX = KS - 8;
  const int tid = threadIdx.x;
  const int lane = tid & 63;
  const int w  = tid >> 6;
  const int mh = w & 1;       // 32-row batch half
  const int nh = w >> 1;      // 16-col half within slice
  const int q  = lane >> 4;
  const int lm = lane & 15;
  const int jcol = ji * 32 + nh * 16 + lm;   // hidden col this lane owns
  const int fin = (l == 0) ? FF : HH;

  // ---- persistent W fragments + bias + c-state ----
  uint4 wf[4][KS];
  float bias[4];
  float creg[2][4];
  #pragma unroll
  for (int g = 0; g < 4; ++g) {
    const int row = g * HH + jcol;
    bias[g] = bih[row] + bhh[row];
    #pragma unroll
    for (int ks = 0; ks < KS; ++ks) {
      const int kb = ks * 32 + q * 8;
      float f[8];
      #pragma unroll
      for (int j = 0; j < 8; ++j) {
        const int k = kb + j;
        if (k < HH) f[j] = Whh[row * HH + k];
        else { const int kk = k - HH; f[j] = (kk < fin) ? Wih[row * fin + kk] : 0.f; }
      }
      wf[g][ks] = pack8(f);
    }
  }
  #pragma unroll
  for (int Mt = 0; Mt < 2; ++Mt)
    #pragma unroll
    for (int r = 0; r < 4; ++r) {
      const int gbrow = bi * BT + mh * 32 + Mt * 16 + q * 4 + r;
      creg[Mt][r] = c0[((size_t)l * BB + gbrow) * HH + jcol];
    }

  const int g = l * NBB + bi;
  u32* flgw = flg + ((g * 2 + mh) * 16 + ji * 2 + nh);
  const u32* pO = flg + (g * 2 + mh) * 16;
  const u32* pL = (l > 0) ? flg + ((g - NBB) * 2 + mh) * 16 : pO;
  const u32* pC = (l < 2) ? cns + (g * 2 + mh) * 16 : pO;
  u32* cnsw = (l > 0) ? cns + ((g - NBB) * 2 + mh) * 16 + ji * 2 + nh : nullptr;
  char* rown = ring + (size_t)g * DSLOT * SLOTB;
  char* rlow = ring + (size_t)(g - NBB) * DSLOT * SLOTB;

  // per-lane A-frag byte offsets within a slot: row*(256*2) + (q*8)*2
  const u32 vo0 = (u32)(((mh * 32 + lm) * 256 + q * 8) * 2);
  const u32 vo1 = vo0 + 16 * 256 * 2;   // +16 rows (Mt=1)
  u32 pub[2][4];
  #pragma unroll
  for (int Mt = 0; Mt < 2; ++Mt)
    #pragma unroll
    for (int r = 0; r < 4; ++r)
      pub[Mt][r] = (u32)(((mh * 32 + Mt * 16 + q * 4 + r) * 256 + jcol) * 2);

  const float* xrow0 = x + (size_t)(bi * BT + mh * 32 + 0 * 16 + lm) * (TT * FF);
  const float* xrow1 = x + (size_t)(bi * BT + mh * 32 + 1 * 16 + lm) * (TT * FF);

  uint4 ha[2][8];
  uint4 xa[2][8];

  // ---- pre-loop: publish h0 into ring slot 7 (== slot (0-1)&7), flag=1 ----
  {
    char* dst = rown + (size_t)7 * SLOTB;
    #pragma unroll
    for (int Mt = 0; Mt < 2; ++Mt)
      #pragma unroll
      for (int r = 0; r < 4; ++r) {
        const int gbrow = bi * BT + mh * 32 + Mt * 16 + q * 4 + r;
        const float v = h0[((size_t)l * BB + gbrow) * HH + jcol];
        const u32 mb = f2bf(v);
        const u32 pb = (u32)__shfl_xor((int)mb, 1, 64);
        if (!(lane & 1)) stg_coh_b32(dst + pub[Mt][r], (mb & 0xffffu) | (pb << 16));
      }
    vm_drain();
    if (lane == 0) stg_coh_b32(flgw, 1u);
  }

  // ---- initial frag loads: xa <- y(0)/x(0); ha <- h0 (slot 7) ----
  pollwait(pO, pL, pC, 1u, (l > 0) ? 2u : 0u, 0u);
  if constexpr (KS == 16) {
    LD16X(rlow);                       // slot 0 = y(0)
  } else {
    #pragma unroll
    for (int Mt = 0; Mt < 2; ++Mt) {
      const float* bp = (Mt ? xrow1 : xrow0);
      #pragma unroll
      for (int kx = 0; kx < KSX; ++kx) {
        float f[8];
        #pragma unroll
        for (int j = 0; j < 8; ++j) {
          const int kk = kx * 32 + q * 8 + j;
          f[j] = (kk < FF) ? bp[kk] : 0.f;
        }
        xa[Mt][kx] = pack8(f);
      }
    }
  }
  LD16H(rown + (size_t)7 * SLOTB);     // drains LD16X loads too
  if (l > 0 && lane == 0) stg_coh_b32(cnsw, 2u);

  // ---- main loop ----
  #pragma unroll 1
  for (int t = 0; t < TT; ++t) {
    const int tn = (t + 1 < TT) ? t + 1 : TT - 1;
    f32x4 z0 = {0.f, 0.f, 0.f, 0.f};
    f32x4 acc[2][4];
    #pragma unroll
    for (int Mt = 0; Mt < 2; ++Mt)
      #pragma unroll
      for (int gg = 0; gg < 4; ++gg) acc[Mt][gg] = z0;

    // x-part MFMA first half; mid: drain publish stores of h(t-1) + set flag; 2nd half
    #pragma unroll
    for (int kx = 0; kx < KSX / 2; ++kx) {
      FragU a0, a1; a0.u = xa[0][kx]; a1.u = xa[1][kx];
      #pragma unroll
      for (int gg = 0; gg < 4; ++gg) {
        FragU b; b.u = wf[gg][8 + kx];
        acc[0][gg] = __builtin_amdgcn_mfma_f32_16x16x32_bf16(a0.b, b.b, acc[0][gg], 0, 0, 0);
        acc[1][gg] = __builtin_amdgcn_mfma_f32_16x16x32_bf16(a1.b, b.b, acc[1][gg], 0, 0, 0);
      }
    }
    vm_drain();
    if (lane == 0) stg_coh_b32(flgw, (u32)(t + 1));  // h(t-1) visible
    #pragma unroll
    for (int kx = KSX / 2; kx < KSX; ++kx) {
      FragU a0, a1; a0.u = xa[0][kx]; a1.u = xa[1][kx];
      #pragma unroll
      for (int gg = 0; gg < 4; ++gg) {
        FragU b; b.u = wf[gg][8 + kx];
        acc[0][gg] = __builtin_amdgcn_mfma_f32_16x16x32_bf16(a0.b, b.b, acc[0][gg], 0, 0, 0);
        acc[1][gg] = __builtin_amdgcn_mfma_f32_16x16x32_bf16(a1.b, b.b, acc[1][gg], 0, 0, 0);
      }
    }

    // wait: own group h(t-1); lower y(tn); consumers done with slot t&7's old h(t-8)
    pollwait(pO, pL, pC, (u32)(t + 1),
             (l > 0) ? (u32)(tn + 2) : 0u,
             (l < 2 && t >= DSLOT) ? (u32)(t - 6) : 0u);

    // prefetch xa <- y(tn)/x(tn); load ha <- h(t-1) [slot (t-1)&7], one drain total
    if constexpr (KS == 16) {
      LD16X(rlow + (size_t)(tn & 7) * SLOTB);
    } else {
      #pragma unroll
      for (int Mt = 0; Mt < 2; ++Mt) {
        const float* bp = (Mt ? xrow1 : xrow0) + (size_t)tn * FF;
        #pragma unroll
        for (int kx = 0; kx < KSX; ++kx) {
          float f[8];
          #pragma unroll
          for (int j = 0; j < 8; ++j) {
            const int kk = kx * 32 + q * 8 + j;
            f[j] = (kk < FF) ? bp[kk] : 0.f;
          }
          xa[Mt][kx] = pack8(f);
        }
      }
    }
    LD16H(rown + (size_t)((t + 7) & 7) * SLOTB);
    if (l > 0 && lane == 0) stg_coh_b32(cnsw, (u32)(tn + 2));  // consumed y(tn)

    // h-part MFMA
    #pragma unroll
    for (int ks = 0; ks < 8; ++ks) {
      FragU a0, a1; a0.u = ha[0][ks]; a1.u = ha[1][ks];
      #pragma unroll
      for (int gg = 0; gg < 4; ++gg) {
        FragU b; b.u = wf[gg][ks];
        acc[0][gg] = __builtin_amdgcn_mfma_f32_16x16x32_bf16(a0.b, b.b, acc[0][gg], 0, 0, 0);
        acc[1][gg] = __builtin_amdgcn_mfma_f32_16x16x32_bf16(a1.b, b.b, acc[1][gg], 0, 0, 0);
      }
    }

    // gates (i,f,g,o in acc[Mt][0..3], same lane/reg) + publish h(t) -> slot t&7
    char* dst = rown + (size_t)(t & 7) * SLOTB;
    #pragma unroll
    for (int Mt = 0; Mt < 2; ++Mt)
      #pragma unroll
      for (int r = 0; r < 4; ++r) {
        const float zi = acc[Mt][0][r] + bias[0];
        const float zf = acc[Mt][1][r] + bias[1];
        const float zg = acc[Mt][2][r] + bias[2];
        const float zo = acc[Mt][3][r] + bias[3];
        const float cn = fsig(zf) * creg[Mt][r] + fsig(zi) * ftanh(zg);
        creg[Mt][r] = cn;
        const float hv = fsig(zo) * ftanh(cn);
        const u32 mb = f2bf(hv);
        const u32 pb = (u32)__shfl_xor((int)mb, 1, 64);
        if (!(lane & 1)) stg_coh_b32(dst + pub[Mt][r], (mb & 0xffffu) | (pb << 16));
        if (t == TT - 1) {
          const int gbrow = bi * BT + mh * 32 + Mt * 16 + q * 4 + r;
          dout[HFIN_OFF + ((size_t)l * BB + gbrow) * HH + jcol] = hv;
          dout[CFIN_OFF + ((size_t)l * BB + gbrow) * HH + jcol] = cn;
        }
      }
  }

  vm_drain();
  if (lane == 0) stg_coh_b32(flgw, (u32)(TT + 1));  // h(TT-1) visible
}

__global__ __launch_bounds__(256, 1) void lstm_kernel(
    const float* __restrict__ x, const float* __restrict__ h0, const float* __restrict__ c0,
    const float* __restrict__ Wih0, const float* __restrict__ Whh0, const float* __restrict__ bih0, const float* __restrict__ bhh0,
    const float* __restrict__ Wih1, const float* __restrict__ Whh1, const float* __restrict__ bih1, const float* __restrict__ bhh1,
    const float* __restrict__ Wih2, const float* __restrict__ Whh2, const float* __restrict__ bih2, const float* __restrict__ bhh2,
    float* __restrict__ dout, u32* flg, u32* cns, char* ring)
{
  const int l  = blockIdx.x >> 5;         // 32 blocks per layer
  const int bi = (blockIdx.x >> 3) & 3;
  const int ji = blockIdx.x & 7;
  const float* Wih = (l == 0) ? Wih0 : (l == 1) ? Wih1 : Wih2;
  const float* Whh = (l == 0) ? Whh0 : (l == 1) ? Whh1 : Whh2;
  const float* bih = (l == 0) ? bih0 : (l == 1) ? bih1 : bih2;
  const float* bhh = (l == 0) ? bhh0 : (l == 1) ? bhh1 : bhh2;
  if (l == 0)
    lstm_body<12>(0, bi, ji, x, h0, c0, Wih, Whh, bih, bhh, dout, flg, cns, ring);
  else
    lstm_body<16>(l, bi, ji, x, h0, c0, Wih, Whh, bih, bhh, dout, flg, cns, ring);
}

__global__ void fc_kernel(const float* __restrict__ dout_r, const float* __restrict__ fcw,
                          const float* __restrict__ fcb, float* __restrict__ out)
{
  const int b = blockIdx.x;
  __shared__ float hrow[HH];
  const float* hs = dout_r + HFIN_OFF + ((size_t)2 * BB + b) * HH;  // ys2[T-1] == h_fin[2]
  for (int i = threadIdx.x; i < HH; i += 64) {
    const float v = hs[i];
    hrow[i] = (v > 0.f) ? v : 0.01f * v;
  }
  __syncthreads();
  if (threadIdx.x < OO) {
    float s = fcb[threadIdx.x];
    #pragma unroll 8
    for (int k = 0; k < HH; ++k) s += hrow[k] * fcw[threadIdx.x * HH + k];
    out[(size_t)b * OO + threadIdx.x] = s;
  }
}

extern "C" void kernel_launch(void* const* d_in, const int* in_sizes, int n_in,
                              void* d_out, int out_size, void* d_ws, size_t ws_size,
                              hipStream_t stream)
{
  (void)in_sizes; (void)n_in; (void)out_size; (void)ws_size;
  const float* x    = (const float*)d_in[0];
  const float* h0   = (const float*)d_in[1];
  const float* c0   = (const float*)d_in[2];
  const float* Wih0 = (const float*)d_in[3];
  const float* Whh0 = (const float*)d_in[4];
  const float* bih0 = (const float*)d_in[5];
  const float* bhh0 = (const float*)d_in[6];
  const float* Wih1 = (const float*)d_in[7];
  const float* Whh1 = (const float*)d_in[8];
  const float* bih1 = (const float*)d_in[9];
  const float* bhh1 = (const float*)d_in[10];
  const float* Wih2 = (const float*)d_in[11];
  const float* Whh2 = (const float*)d_in[12];
  const float* bih2 = (const float*)d_in[13];
  const float* bhh2 = (const float*)d_in[14];
  const float* fcw  = (const float*)d_in[15];
  const float* fcb  = (const float*)d_in[16];
  float* out = (float*)d_out;

  // ws layout: [0,4KB) flg[12][2][16]; [4KB,8KB) cns; ring @ 8KB (12*8*32KB = 3MB)
  u32* flg  = (u32*)d_ws;
  u32* cns  = (u32*)((char*)d_ws + 4096);
  char* ring = (char*)d_ws + 8192;

  (void)hipMemsetAsync(d_ws, 0, 8192, stream);  // zero flag regions (ws 0xAA-poisoned)
  hipLaunchKernelGGL(lstm_kernel, dim3(3 * NBB * NJ), dim3(256), 0, stream,
                     x, h0, c0, Wih0, Whh0, bih0, bhh0, Wih1, Whh1, bih1, bhh1,
                     Wih2, Whh2, bih2, bhh2, out, flg, cns, ring);
  hipLaunchKernelGGL(fc_kernel, dim3(BB), dim3(64), 0, stream, out, fcw, fcb, out);
}

// Round 8
// 7559.859 us; speedup vs baseline: 1.5947x; 1.5947x over previous
//
#include <hip/hip_runtime.h>
#include <hip/hip_bf16.h>

typedef __attribute__((ext_vector_type(8))) short bf16x8;
typedef __attribute__((ext_vector_type(4))) float f32x4;
typedef unsigned int u32;
typedef unsigned long long u64;

static constexpr int TT = 1024, BB = 256, HH = 256, FF = 73, OO = 35;
static constexpr int NBB = 8;   // batch tiles (32 rows each)
static constexpr int NJ = 8;    // gate-slice blocks per tile (32 cols)
static constexpr int BT = 32;   // batch rows per block
static constexpr int DSLOT = 8; // ring depth
static constexpr int SLOTB = BT * HH * 2;  // 16384 B per slot [32 rows][256 cols] bf16
static constexpr int HFIN_OFF = BB * OO;
static constexpr int CFIN_OFF = HFIN_OFF + 3 * BB * HH;

union FragU { uint4 u; bf16x8 b; };

__device__ __forceinline__ unsigned short f2bf(float f) {
  __hip_bfloat16 h = __float2bfloat16(f);
  union { __hip_bfloat16 h; unsigned short s; } cv; cv.h = h; return cv.s;
}
__device__ __forceinline__ u32 pk2(float a, float b) {
  return (u32)f2bf(a) | ((u32)f2bf(b) << 16);
}
__device__ __forceinline__ uint4 pack8(const float* f) {
  return make_uint4(pk2(f[0], f[1]), pk2(f[2], f[3]), pk2(f[4], f[5]), pk2(f[6], f[7]));
}
__device__ __forceinline__ float fsig(float x) { return 1.f / (1.f + __expf(-x)); }
__device__ __forceinline__ float ftanh(float x) { return 2.f * fsig(2.f * x) - 1.f; }

__device__ __forceinline__ void stg_coh_b32(void* p, u32 v) {
  asm volatile("global_store_dword %0, %1, off sc0 sc1" :: "v"(p), "v"(v) : "memory");
}
__device__ __forceinline__ void vm_drain() {
  asm volatile("s_waitcnt vmcnt(0)" ::: "memory");
}
__device__ __forceinline__ bool ge4(uint4 v, u32 n) {
  return v.x >= n && v.y >= n && v.z >= n && v.w >= n;
}

// Poll three 64B flag regions (own / lower / consumer) in one coherent burst.
// sc0 sc1 on poll loads is mandatory (round-6 hang: stale per-XCD L2 otherwise).
__device__ __forceinline__ void pollwait(const u32* pO, const u32* pL, const u32* pC,
                                         u32 nO, u32 nL, u32 nC) {
  for (u32 it = 0; it < 500000u; ++it) {
    uint4 a0, a1, a2, a3, b0, b1, b2, b3, c0, c1, c2, c3;
    asm volatile(
        "global_load_dwordx4 %0, %12, off sc0 sc1\n\t"
        "global_load_dwordx4 %1, %12, off offset:16 sc0 sc1\n\t"
        "global_load_dwordx4 %2, %12, off offset:32 sc0 sc1\n\t"
        "global_load_dwordx4 %3, %12, off offset:48 sc0 sc1\n\t"
        "global_load_dwordx4 %4, %13, off sc0 sc1\n\t"
        "global_load_dwordx4 %5, %13, off offset:16 sc0 sc1\n\t"
        "global_load_dwordx4 %6, %13, off offset:32 sc0 sc1\n\t"
        "global_load_dwordx4 %7, %13, off offset:48 sc0 sc1\n\t"
        "global_load_dwordx4 %8, %14, off sc0 sc1\n\t"
        "global_load_dwordx4 %9, %14, off offset:16 sc0 sc1\n\t"
        "global_load_dwordx4 %10, %14, off offset:32 sc0 sc1\n\t"
        "global_load_dwordx4 %11, %14, off offset:48 sc0 sc1\n\t"
        "s_waitcnt vmcnt(0)"
        : "=&v"(a0), "=&v"(a1), "=&v"(a2), "=&v"(a3),
          "=&v"(b0), "=&v"(b1), "=&v"(b2), "=&v"(b3),
          "=&v"(c0), "=&v"(c1), "=&v"(c2), "=&v"(c3)
        : "v"(pO), "v"(pL), "v"(pC)
        : "memory");
    if (ge4(a0, nO) && ge4(a1, nO) && ge4(a2, nO) && ge4(a3, nO) &&
        ge4(b0, nL) && ge4(b1, nL) && ge4(b2, nL) && ge4(b3, nL) &&
        ge4(c0, nC) && ge4(c1, nC) && ge4(c2, nC) && ge4(c3, nC)) return;
    __builtin_amdgcn_s_sleep(1);
  }
  // bound tripped: fall through (finite wrong answer beats an infinite hang)
}

// xa burst: 8 loads in flight, NO waitcnt (drained by the following LD8H).
#define LD8X(basep)                                                             \
  do {                                                                          \
    const char* _x0 = (basep) + vo;                                             \
    asm volatile(                                                               \
        "global_load_dwordx4 %0, %8, off sc0 sc1\n\t"                           \
        "global_load_dwordx4 %1, %8, off offset:64 sc0 sc1\n\t"                 \
        "global_load_dwordx4 %2, %8, off offset:128 sc0 sc1\n\t"                \
        "global_load_dwordx4 %3, %8, off offset:192 sc0 sc1\n\t"                \
        "global_load_dwordx4 %4, %8, off offset:256 sc0 sc1\n\t"                \
        "global_load_dwordx4 %5, %8, off offset:320 sc0 sc1\n\t"                \
        "global_load_dwordx4 %6, %8, off offset:384 sc0 sc1\n\t"                \
        "global_load_dwordx4 %7, %8, off offset:448 sc0 sc1"                    \
        : "=&v"(xa[0]), "=&v"(xa[1]), "=&v"(xa[2]), "=&v"(xa[3]),               \
          "=&v"(xa[4]), "=&v"(xa[5]), "=&v"(xa[6]), "=&v"(xa[7])                \
        : "v"(_x0)                                                              \
        : "memory");                                                            \
  } while (0)

// ha burst: 8 loads + vmcnt(0) (drains the LD8X loads too).
#define LD8H(basep)                                                             \
  do {                                                                          \
    const char* _h0 = (basep) + vo;                                             \
    asm volatile(                                                               \
        "global_load_dwordx4 %0, %8, off sc0 sc1\n\t"                           \
        "global_load_dwordx4 %1, %8, off offset:64 sc0 sc1\n\t"                 \
        "global_load_dwordx4 %2, %8, off offset:128 sc0 sc1\n\t"                \
        "global_load_dwordx4 %3, %8, off offset:192 sc0 sc1\n\t"                \
        "global_load_dwordx4 %4, %8, off offset:256 sc0 sc1\n\t"                \
        "global_load_dwordx4 %5, %8, off offset:320 sc0 sc1\n\t"                \
        "global_load_dwordx4 %6, %8, off offset:384 sc0 sc1\n\t"                \
        "global_load_dwordx4 %7, %8, off offset:448 sc0 sc1\n\t"                \
        "s_waitcnt vmcnt(0)"                                                    \
        : "=&v"(ha[0]), "=&v"(ha[1]), "=&v"(ha[2]), "=&v"(ha[3]),               \
          "=&v"(ha[4]), "=&v"(ha[5]), "=&v"(ha[6]), "=&v"(ha[7])                \
        : "v"(_h0)                                                              \
        : "memory");                                                            \
  } while (0)

// One block = (layer l, 32-row batch tile bi, 32-col gate slice ji); 4 autonomous
// waves (mt = 16-row half, hh2 = 16-col half). No LDS, no __syncthreads. Per-wave
// footprint sized to avoid spill: ha/xa 8 uint4 each, wf -> AGPRs.
template <int KS>  // 16 for l>0 (K=512), 12 for l0 (K=384)
__device__ void lstm_body(int l, int bi, int ji,
    const float* __restrict__ x,
    const float* __restrict__ h0, const float* __restrict__ c0,
    const float* __restrict__ Wih, const float* __restrict__ Whh,
    const float* __restrict__ bih, const float* __restrict__ bhh,
    float* __restrict__ dout, u32* flg, u32* cns, char* ring)
{
  constexpr int KSX = KS - 8;
  const int tid = threadIdx.x;
  const int lane = tid & 63;
  const int w   = tid >> 6;
  const int mt  = w & 1;      // 16-row batch half
  const int hh2 = w >> 1;     // 16-col half within slice
  const int q   = lane >> 4;
  const int lm  = lane & 15;
  const int jcol = ji * 32 + hh2 * 16 + lm;  // hidden col this lane owns
  const int fin = (l == 0) ? FF : HH;

  // ---- persistent W fragments + bias + c-state ----
  uint4 wf[4][KS];
  float bias[4];
  float creg[4];
  #pragma unroll
  for (int g = 0; g < 4; ++g) {
    const int row = g * HH + jcol;
    bias[g] = bih[row] + bhh[row];
    #pragma unroll
    for (int ks = 0; ks < KS; ++ks) {
      const int kb = ks * 32 + q * 8;
      float f[8];
      #pragma unroll
      for (int j = 0; j < 8; ++j) {
        const int k = kb + j;
        if (k < HH) f[j] = Whh[row * HH + k];
        else { const int kk = k - HH; f[j] = (kk < fin) ? Wih[row * fin + kk] : 0.f; }
      }
      wf[g][ks] = pack8(f);
    }
  }
  #pragma unroll
  for (int r = 0; r < 4; ++r) {
    const int gbrow = bi * BT + mt * 16 + q * 4 + r;
    creg[r] = c0[((size_t)l * BB + gbrow) * HH + jcol];
  }

  const int g = l * NBB + bi;
  u32* flgw = flg + ((g * 2 + mt) * 16 + ji * 2 + hh2);
  const u32* pO = flg + (g * 2 + mt) * 16;
  const u32* pL = (l > 0) ? flg + ((g - NBB) * 2 + mt) * 16 : pO;
  const u32* pC = (l < 2) ? cns + (g * 2 + mt) * 16 : pO;
  u32* cnsw = (l > 0) ? cns + ((g - NBB) * 2 + mt) * 16 + ji * 2 + hh2 : nullptr;
  char* rown = ring + (size_t)g * DSLOT * SLOTB;
  char* rlow = ring + (size_t)(g - NBB) * DSLOT * SLOTB;

  // per-lane A-frag byte offset within a slot: row*(256*2) + (q*8)*2
  const u32 vo = (u32)(((mt * 16 + lm) * 256 + q * 8) * 2);
  u32 pub[4];
  #pragma unroll
  for (int r = 0; r < 4; ++r)
    pub[r] = (u32)(((mt * 16 + q * 4 + r) * 256 + jcol) * 2);

  const float* xrow = x + (size_t)(bi * BT + mt * 16 + lm) * (TT * FF);

  uint4 ha[8];
  uint4 xa[8];

  // ---- pre-loop: publish h0 into ring slot 7, flag=1 ----
  {
    char* dst = rown + (size_t)7 * SLOTB;
    #pragma unroll
    for (int r = 0; r < 4; ++r) {
      const int gbrow = bi * BT + mt * 16 + q * 4 + r;
      const float v = h0[((size_t)l * BB + gbrow) * HH + jcol];
      const u32 mb = f2bf(v);
      const u32 pb = (u32)__shfl_xor((int)mb, 1, 64);
      if (!(lane & 1)) stg_coh_b32(dst + pub[r], (mb & 0xffffu) | (pb << 16));
    }
    vm_drain();
    if (lane == 0) stg_coh_b32(flgw, 1u);
  }

  // ---- initial frag loads: xa <- y(0)/x(0); ha <- h0 (slot 7) ----
  pollwait(pO, pL, pC, 1u, (l > 0) ? 2u : 0u, 0u);
  if constexpr (KS == 16) {
    LD8X(rlow);                        // slot 0 = y(0)
  } else {
    #pragma unroll
    for (int kx = 0; kx < KSX; ++kx) {
      float f[8];
      #pragma unroll
      for (int j = 0; j < 8; ++j) {
        const int kk = kx * 32 + q * 8 + j;
        f[j] = (kk < FF) ? xrow[kk] : 0.f;
      }
      xa[kx] = pack8(f);
    }
  }
  LD8H(rown + (size_t)7 * SLOTB);      // drains LD8X too
  if (l > 0 && lane == 0) stg_coh_b32(cnsw, 2u);

  // ---- main loop ----
  #pragma unroll 1
  for (int t = 0; t < TT; ++t) {
    const int tn = (t + 1 < TT) ? t + 1 : TT - 1;
    f32x4 z0 = {0.f, 0.f, 0.f, 0.f};
    f32x4 acc[4] = {z0, z0, z0, z0};

    // x-part MFMA 1st half; mid: drain publish of h(t-1) + set flag; 2nd half
    #pragma unroll
    for (int kx = 0; kx < KSX / 2; ++kx) {
      FragU a; a.u = xa[kx];
      #pragma unroll
      for (int gg = 0; gg < 4; ++gg) {
        FragU b; b.u = wf[gg][8 + kx];
        acc[gg] = __builtin_amdgcn_mfma_f32_16x16x32_bf16(a.b, b.b, acc[gg], 0, 0, 0);
      }
    }
    vm_drain();
    if (lane == 0) stg_coh_b32(flgw, (u32)(t + 1));  // h(t-1) visible
    #pragma unroll
    for (int kx = KSX / 2; kx < KSX; ++kx) {
      FragU a; a.u = xa[kx];
      #pragma unroll
      for (int gg = 0; gg < 4; ++gg) {
        FragU b; b.u = wf[gg][8 + kx];
        acc[gg] = __builtin_amdgcn_mfma_f32_16x16x32_bf16(a.b, b.b, acc[gg], 0, 0, 0);
      }
    }

    // layer-0: pack x(tn) now (plain cached loads, off the coherent chain)
    if constexpr (KS == 12) {
      const float* bp = xrow + (size_t)tn * FF;
      #pragma unroll
      for (int kx = 0; kx < KSX; ++kx) {
        float f[8];
        #pragma unroll
        for (int j = 0; j < 8; ++j) {
          const int kk = kx * 32 + q * 8 + j;
          f[j] = (kk < FF) ? bp[kk] : 0.f;
        }
        xa[kx] = pack8(f);
      }
    }

    // wait: own group h(t-1); lower y(tn); consumers done with slot t&7's h(t-8)
    pollwait(pO, pL, pC, (u32)(t + 1),
             (l > 0) ? (u32)(tn + 2) : 0u,
             (l < 2 && t >= DSLOT) ? (u32)(t - 6) : 0u);

    // prefetch xa <- y(tn) (l>0); load ha <- h(t-1) [slot (t-1)&7]; one drain
    if constexpr (KS == 16) {
      LD8X(rlow + (size_t)(tn & 7) * SLOTB);
    }
    LD8H(rown + (size_t)((t + 7) & 7) * SLOTB);
    if (l > 0 && lane == 0) stg_coh_b32(cnsw, (u32)(tn + 2));  // consumed y(tn)

    // h-part MFMA
    #pragma unroll
    for (int ks = 0; ks < 8; ++ks) {
      FragU a; a.u = ha[ks];
      #pragma unroll
      for (int gg = 0; gg < 4; ++gg) {
        FragU b; b.u = wf[gg][ks];
        acc[gg] = __builtin_amdgcn_mfma_f32_16x16x32_bf16(a.b, b.b, acc[gg], 0, 0, 0);
      }
    }

    // gates (i,f,g,o in acc[0..3], same lane/reg) + publish h(t) -> slot t&7
    char* dst = rown + (size_t)(t & 7) * SLOTB;
    #pragma unroll
    for (int r = 0; r < 4; ++r) {
      const float zi = acc[0][r] + bias[0];
      const float zf = acc[1][r] + bias[1];
      const float zg = acc[2][r] + bias[2];
      const float zo = acc[3][r] + bias[3];
      const float cn = fsig(zf) * creg[r] + fsig(zi) * ftanh(zg);
      creg[r] = cn;
      const float hv = fsig(zo) * ftanh(cn);
      const u32 mb = f2bf(hv);
      const u32 pb = (u32)__shfl_xor((int)mb, 1, 64);
      if (!(lane & 1)) stg_coh_b32(dst + pub[r], (mb & 0xffffu) | (pb << 16));
      if (t == TT - 1) {
        const int gbrow = bi * BT + mt * 16 + q * 4 + r;
        dout[HFIN_OFF + ((size_t)l * BB + gbrow) * HH + jcol] = hv;
        dout[CFIN_OFF + ((size_t)l * BB + gbrow) * HH + jcol] = cn;
      }
    }
  }

  vm_drain();
  if (lane == 0) stg_coh_b32(flgw, (u32)(TT + 1));  // h(TT-1) visible
}

__global__ __launch_bounds__(256, 1) void lstm_kernel(
    const float* __restrict__ x, const float* __restrict__ h0, const float* __restrict__ c0,
    const float* __restrict__ Wih0, const float* __restrict__ Whh0, const float* __restrict__ bih0, const float* __restrict__ bhh0,
    const float* __restrict__ Wih1, const float* __restrict__ Whh1, const float* __restrict__ bih1, const float* __restrict__ bhh1,
    const float* __restrict__ Wih2, const float* __restrict__ Whh2, const float* __restrict__ bih2, const float* __restrict__ bhh2,
    float* __restrict__ dout, u32* flg, u32* cns, char* ring)
{
  const int l  = blockIdx.x >> 6;         // 64 blocks per layer
  const int bi = (blockIdx.x >> 3) & 7;
  const int ji = blockIdx.x & 7;
  const float* Wih = (l == 0) ? Wih0 : (l == 1) ? Wih1 : Wih2;
  const float* Whh = (l == 0) ? Whh0 : (l == 1) ? Whh1 : Whh2;
  const float* bih = (l == 0) ? bih0 : (l == 1) ? bih1 : bih2;
  const float* bhh = (l == 0) ? bhh0 : (l == 1) ? bhh1 : bhh2;
  if (l == 0)
    lstm_body<12>(0, bi, ji, x, h0, c0, Wih, Whh, bih, bhh, dout, flg, cns, ring);
  else
    lstm_body<16>(l, bi, ji, x, h0, c0, Wih, Whh, bih, bhh, dout, flg, cns, ring);
}

__global__ void fc_kernel(const float* __restrict__ dout_r, const float* __restrict__ fcw,
                          const float* __restrict__ fcb, float* __restrict__ out)
{
  const int b = blockIdx.x;
  __shared__ float hrow[HH];
  const float* hs = dout_r + HFIN_OFF + ((size_t)2 * BB + b) * HH;  // ys2[T-1] == h_fin[2]
  for (int i = threadIdx.x; i < HH; i += 64) {
    const float v = hs[i];
    hrow[i] = (v > 0.f) ? v : 0.01f * v;
  }
  __syncthreads();
  if (threadIdx.x < OO) {
    float s = fcb[threadIdx.x];
    #pragma unroll 8
    for (int k = 0; k < HH; ++k) s += hrow[k] * fcw[threadIdx.x * HH + k];
    out[(size_t)b * OO + threadIdx.x] = s;
  }
}

extern "C" void kernel_launch(void* const* d_in, const int* in_sizes, int n_in,
                              void* d_out, int out_size, void* d_ws, size_t ws_size,
                              hipStream_t stream)
{
  (void)in_sizes; (void)n_in; (void)out_size; (void)ws_size;
  const float* x    = (const float*)d_in[0];
  const float* h0   = (const float*)d_in[1];
  const float* c0   = (const float*)d_in[2];
  const float* Wih0 = (const float*)d_in[3];
  const float* Whh0 = (const float*)d_in[4];
  const float* bih0 = (const float*)d_in[5];
  const float* bhh0 = (const float*)d_in[6];
  const float* Wih1 = (const float*)d_in[7];
  const float* Whh1 = (const float*)d_in[8];
  const float* bih1 = (const float*)d_in[9];
  const float* bhh1 = (const float*)d_in[10];
  const float* Wih2 = (const float*)d_in[11];
  const float* Whh2 = (const float*)d_in[12];
  const float* bih2 = (const float*)d_in[13];
  const float* bhh2 = (const float*)d_in[14];
  const float* fcw  = (const float*)d_in[15];
  const float* fcb  = (const float*)d_in[16];
  float* out = (float*)d_out;

  // ws layout: [0,6KB) flg[24][2][16]; [8KB,14KB) cns; ring @ 16KB (24*8*16KB = 3MB)
  u32* flg  = (u32*)d_ws;
  u32* cns  = (u32*)((char*)d_ws + 8192);
  char* ring = (char*)d_ws + 16384;

  (void)hipMemsetAsync(d_ws, 0, 16384, stream);  // zero flag regions (ws 0xAA-poisoned)
  hipLaunchKernelGGL(lstm_kernel, dim3(3 * NBB * NJ), dim3(256), 0, stream,
                     x, h0, c0, Wih0, Whh0, bih0, bhh0, Wih1, Whh1, bih1, bhh1,
                     Wih2, Whh2, bih2, bhh2, out, flg, cns, ring);
  hipLaunchKernelGGL(fc_kernel, dim3(BB), dim3(64), 0, stream, out, fcw, fcb, out);
}